// Round 2
// baseline (380.524 us; speedup 1.0000x reference)
//
#include <hip/hip_runtime.h>

// WeightedKappaLoss: kappa = 1 - (N * sum(W*conf)) / sum(W_ij * ht_i * hp_j)
// conf = 6x6 confusion histogram of (y_true, argmax(y_pred_row)).
// softmax is monotone -> argmax on raw logits. All counts exact integers;
// final ratio in double -> ~1e-15 rel error vs reference.

#define NC 6
#define NBINS 36
#define GRID 1024   // 4 blocks/CU on 256 CUs; each block emits one 36-bin partial

__global__ void kappa_count_kernel(const float4* __restrict__ yp4,
                                   const int2* __restrict__ yt2,
                                   const float* __restrict__ yp,
                                   const int* __restrict__ yt,
                                   unsigned int* __restrict__ gconf,
                                   int npairs, int N) {
    __shared__ unsigned int sconf[NBINS];
    const int tid = threadIdx.x;
    if (tid < NBINS) sconf[tid] = 0u;
    __syncthreads();

    const int stride = gridDim.x * blockDim.x;
    for (int i = blockIdx.x * blockDim.x + tid; i < npairs; i += stride) {
        const float4 a = yp4[3 * i];
        const float4 b = yp4[3 * i + 1];
        const float4 c = yp4[3 * i + 2];
        const int2 t = yt2[i];

        // row 0: a.x a.y a.z a.w b.x b.y  (strict > keeps first max = jnp.argmax)
        float m = a.x; int p = 0;
        if (a.y > m) { m = a.y; p = 1; }
        if (a.z > m) { m = a.z; p = 2; }
        if (a.w > m) { m = a.w; p = 3; }
        if (b.x > m) { m = b.x; p = 4; }
        if (b.y > m) { m = b.y; p = 5; }
        atomicAdd(&sconf[t.x * NC + p], 1u);

        // row 1: b.z b.w c.x c.y c.z c.w
        m = b.z; p = 0;
        if (b.w > m) { m = b.w; p = 1; }
        if (c.x > m) { m = c.x; p = 2; }
        if (c.y > m) { m = c.y; p = 3; }
        if (c.z > m) { m = c.z; p = 4; }
        if (c.w > m) { m = c.w; p = 5; }
        atomicAdd(&sconf[t.y * NC + p], 1u);
    }

    // odd-N tail (N=4e6 is even; kept for generality)
    if ((N & 1) && blockIdx.x == 0 && tid == 0) {
        const int r = N - 1;
        float m = yp[r * NC]; int p = 0;
        #pragma unroll
        for (int j = 1; j < NC; ++j) {
            const float v = yp[r * NC + j];
            if (v > m) { m = v; p = j; }
        }
        atomicAdd(&sconf[yt[r] * NC + p], 1u);
    }

    __syncthreads();
    // Race-free per-block writedown: contiguous 144 B, coalesced. No global
    // atomics, no prior memset needed (every slot written every launch).
    if (tid < NBINS) gconf[blockIdx.x * NBINS + tid] = sconf[tid];
}

__global__ void kappa_final_kernel(const unsigned int* __restrict__ gconf,
                                   float* __restrict__ out, long long N) {
    __shared__ long long conf_s[NBINS];
    const int tid = threadIdx.x;  // one 64-wide wave
    if (tid < NBINS) {
        long long s = 0;
        // lanes 0..35 read contiguous 144 B per iteration; 144 KB total, L2-hot
        for (int b = 0; b < GRID; ++b) s += (long long)gconf[b * NBINS + tid];
        conf_s[tid] = s;
    }
    __syncthreads();
    if (tid == 0) {
        long long conf[NBINS], ht[NC], hp[NC];
        #pragma unroll
        for (int i = 0; i < NC; ++i) { ht[i] = 0; hp[i] = 0; }
        #pragma unroll
        for (int k = 0; k < NBINS; ++k) conf[k] = conf_s[k];

        long long num = 0;
        #pragma unroll
        for (int i = 0; i < NC; ++i)
            #pragma unroll
            for (int j = 0; j < NC; ++j) {
                const long long w = (long long)(i - j) * (i - j);
                num += w * conf[i * NC + j];
                ht[i] += conf[i * NC + j];
                hp[j] += conf[i * NC + j];
            }
        long long den = 0;
        #pragma unroll
        for (int i = 0; i < NC; ++i)
            #pragma unroll
            for (int j = 0; j < NC; ++j)
                den += (long long)(i - j) * (i - j) * ht[i] * hp[j];

        out[0] = (float)(1.0 - ((double)num * (double)N) / (double)den);
    }
}

extern "C" void kernel_launch(void* const* d_in, const int* in_sizes, int n_in,
                              void* d_out, int out_size, void* d_ws, size_t ws_size,
                              hipStream_t stream) {
    const float* yp = (const float*)d_in[0];
    const int* yt = (const int*)d_in[1];   // int32 on device (verified R1: absmax=0)
    const int N = in_sizes[1];
    unsigned int* gconf = (unsigned int*)d_ws;  // GRID*NBINS uints = 144 KB

    const int npairs = N / 2;
    kappa_count_kernel<<<GRID, 256, 0, stream>>>(
        (const float4*)yp, (const int2*)yt, yp, yt, gconf, npairs, N);
    kappa_final_kernel<<<1, 64, 0, stream>>>(gconf, (float*)d_out, (long long)N);
}

// Round 3
// 155.025 us; speedup vs baseline: 2.4546x; 2.4546x over previous
//
#include <hip/hip_runtime.h>

// WeightedKappaLoss: kappa = 1 - (N * sum(W*conf)) / sum(W_ij * ht_i * hp_j)
// conf = 6x6 confusion histogram of (y_true, argmax(y_pred_row)).
// softmax is monotone -> argmax on raw logits. All counts exact integers;
// final ratio in double -> ~1e-15 rel error vs reference. (R1: absmax == 0)

#define NC 6
#define NBINS 36
#define GRID 1024          // count blocks; each emits one 36-bin partial
#define SEGS 16            // stage-2 segments over the 1024 partials
#define FIN_THREADS (NBINS * SEGS)  // 576 = 9 waves

__global__ void kappa_count_kernel(const float4* __restrict__ yp4,
                                   const int2* __restrict__ yt2,
                                   const float* __restrict__ yp,
                                   const int* __restrict__ yt,
                                   unsigned int* __restrict__ gconf,
                                   int npairs, int N) {
    __shared__ unsigned int sconf[NBINS];
    const int tid = threadIdx.x;
    if (tid < NBINS) sconf[tid] = 0u;
    __syncthreads();

    const int stride = gridDim.x * blockDim.x;
    for (int i = blockIdx.x * blockDim.x + tid; i < npairs; i += stride) {
        const float4 a = yp4[3 * i];
        const float4 b = yp4[3 * i + 1];
        const float4 c = yp4[3 * i + 2];
        const int2 t = yt2[i];

        // row 0: a.x a.y a.z a.w b.x b.y  (strict > keeps first max = jnp.argmax)
        float m = a.x; int p = 0;
        if (a.y > m) { m = a.y; p = 1; }
        if (a.z > m) { m = a.z; p = 2; }
        if (a.w > m) { m = a.w; p = 3; }
        if (b.x > m) { m = b.x; p = 4; }
        if (b.y > m) { m = b.y; p = 5; }
        atomicAdd(&sconf[t.x * NC + p], 1u);

        // row 1: b.z b.w c.x c.y c.z c.w
        m = b.z; p = 0;
        if (b.w > m) { m = b.w; p = 1; }
        if (c.x > m) { m = c.x; p = 2; }
        if (c.y > m) { m = c.y; p = 3; }
        if (c.z > m) { m = c.z; p = 4; }
        if (c.w > m) { m = c.w; p = 5; }
        atomicAdd(&sconf[t.y * NC + p], 1u);
    }

    // odd-N tail (N=4e6 is even; kept for generality)
    if ((N & 1) && blockIdx.x == 0 && tid == 0) {
        const int r = N - 1;
        float m = yp[r * NC]; int p = 0;
        #pragma unroll
        for (int j = 1; j < NC; ++j) {
            const float v = yp[r * NC + j];
            if (v > m) { m = v; p = j; }
        }
        atomicAdd(&sconf[yt[r] * NC + p], 1u);
    }

    __syncthreads();
    // Race-free per-block writedown: contiguous 144 B, coalesced. No global
    // atomics, no prior memset needed (every slot written every launch).
    if (tid < NBINS) gconf[blockIdx.x * NBINS + tid] = sconf[tid];
}

__global__ void kappa_final_kernel(const unsigned int* __restrict__ gconf,
                                   float* __restrict__ out, long long N) {
    // Stage 2a: 576 threads, each sums 64 of the 1024 partials for one bin.
    // Independent unrolled loads + 9 waves -> latency hidden (R2's 236 us was
    // a single-wave serial-load loop; this is the fix).
    __shared__ unsigned int part[SEGS][NBINS];
    __shared__ unsigned int conf_s[NBINS];
    const int tid = threadIdx.x;
    if (tid < FIN_THREADS) {
        const int bin = tid % NBINS;
        const int seg = tid / NBINS;
        unsigned int s = 0;
        const int b0 = seg * (GRID / SEGS);
        #pragma unroll 8
        for (int b = b0; b < b0 + GRID / SEGS; ++b) s += gconf[b * NBINS + bin];
        part[seg][bin] = s;
    }
    __syncthreads();
    if (tid < NBINS) {
        unsigned int tot = 0;
        #pragma unroll
        for (int s2 = 0; s2 < SEGS; ++s2) tot += part[s2][tid];
        conf_s[tid] = tot;   // per-bin total <= N=4e6, exact in u32
    }
    __syncthreads();
    if (tid == 0) {
        long long conf[NBINS], ht[NC], hp[NC];
        #pragma unroll
        for (int i = 0; i < NC; ++i) { ht[i] = 0; hp[i] = 0; }
        #pragma unroll
        for (int k = 0; k < NBINS; ++k) conf[k] = (long long)conf_s[k];

        long long num = 0;
        #pragma unroll
        for (int i = 0; i < NC; ++i)
            #pragma unroll
            for (int j = 0; j < NC; ++j) {
                const long long w = (long long)(i - j) * (i - j);
                num += w * conf[i * NC + j];
                ht[i] += conf[i * NC + j];
                hp[j] += conf[i * NC + j];
            }
        long long den = 0;
        #pragma unroll
        for (int i = 0; i < NC; ++i)
            #pragma unroll
            for (int j = 0; j < NC; ++j)
                den += (long long)(i - j) * (i - j) * ht[i] * hp[j];

        out[0] = (float)(1.0 - ((double)num * (double)N) / (double)den);
    }
}

extern "C" void kernel_launch(void* const* d_in, const int* in_sizes, int n_in,
                              void* d_out, int out_size, void* d_ws, size_t ws_size,
                              hipStream_t stream) {
    const float* yp = (const float*)d_in[0];
    const int* yt = (const int*)d_in[1];   // int32 on device (verified R1: absmax=0)
    const int N = in_sizes[1];
    unsigned int* gconf = (unsigned int*)d_ws;  // GRID*NBINS uints = 144 KB

    const int npairs = N / 2;
    kappa_count_kernel<<<GRID, 256, 0, stream>>>(
        (const float4*)yp, (const int2*)yt, yp, yt, gconf, npairs, N);
    kappa_final_kernel<<<1, FIN_THREADS, 0, stream>>>(gconf, (float*)d_out,
                                                      (long long)N);
}